// Round 7
// baseline (5768.483 us; speedup 1.0000x reference)
//
#include <hip/hip_runtime.h>

#define N_PTS 16384
#define M_TOTAL 8192
#define M1 4096

// output offsets (floats)
#define OUT_NP   0
#define OUT_X1   12288
#define OUT_NO   536576
#define OUT_NP2  536577
#define OUT_X2   548865
#define OUT_NO2  1073153

#define POOL_C 64

// ---------------- K0: |p|^2, SoA copy, n_o outputs, flag + fidx init ----------------
__global__ void k0_init(const float* __restrict__ p, float* __restrict__ sump,
                        float* __restrict__ px, float* __restrict__ py, float* __restrict__ pz,
                        float* __restrict__ out, int* __restrict__ flag, int* __restrict__ fidx) {
    int i = blockIdx.x * 256 + threadIdx.x;
    if (i == 0) { out[OUT_NO] = 4096.0f; out[OUT_NO2] = 4096.0f; atomicExch(flag, 0); }
    if (i < M_TOTAL) fidx[i] = (i == 0) ? 0 : -1;   // -1 = not yet produced (worker handshake)
    if (i < N_PTS) {
        float x = p[3*i], y = p[3*i+1], z = p[3*i+2];
        px[i] = x; py[i] = y; pz[i] = z;
        sump[i] = __fadd_rn(__fadd_rn(__fmul_rn(x,x), __fmul_rn(y,y)), __fmul_rn(z,z));
    }
}

__device__ __forceinline__ unsigned spread4(unsigned v) {
    return (v & 1u) | ((v & 2u) << 2) | ((v & 4u) << 4) | ((v & 8u) << 6);
}
// exact lower bound: rn ops, monotone rounding => d2bb <= d2(p,q) for p in bbox
__device__ __forceinline__ float bb_d2(float qx, float qy, float qz,
                                       float mnx, float mxx, float mny, float mxy,
                                       float mnz, float mxz) {
    float ax = fmaxf(fmaxf(__fsub_rn(mnx, qx), __fsub_rn(qx, mxx)), 0.0f);
    float ay = fmaxf(fmaxf(__fsub_rn(mny, qy), __fsub_rn(qy, mxy)), 0.0f);
    float az = fmaxf(fmaxf(__fsub_rn(mnz, qz), __fsub_rn(qz, mxz)), 0.0f);
    return __fadd_rn(__fadd_rn(__fmul_rn(ax,ax), __fmul_rn(ay,ay)), __fmul_rn(az,az));
}
// exact np replication: (dx*dx + dy*dy) + dz*dz, rn, no FMA
__device__ __forceinline__ float pt_d2(float ax, float ay, float az,
                                       float bx, float by, float bz) {
    float dx = __fsub_rn(ax,bx), dy = __fsub_rn(ay,by), dz = __fsub_rn(az,bz);
    return __fadd_rn(__fadd_rn(__fmul_rn(dx,dx), __fmul_rn(dy,dy)), __fmul_rn(dz,dz));
}
// wave64 max via DPP (row_shr 1,2,4,8 ; row_bcast15 ; row_bcast31), broadcast from lane63
__device__ __forceinline__ float wave_max64(float v) {
    v = fmaxf(v, __int_as_float(__builtin_amdgcn_update_dpp(0, __float_as_int(v), 0x111, 0xf, 0xf, true)));
    v = fmaxf(v, __int_as_float(__builtin_amdgcn_update_dpp(0, __float_as_int(v), 0x112, 0xf, 0xf, true)));
    v = fmaxf(v, __int_as_float(__builtin_amdgcn_update_dpp(0, __float_as_int(v), 0x114, 0xf, 0xf, true)));
    v = fmaxf(v, __int_as_float(__builtin_amdgcn_update_dpp(0, __float_as_int(v), 0x118, 0xf, 0xf, true)));
    v = fmaxf(v, __int_as_float(__builtin_amdgcn_update_dpp(0, __float_as_int(v), 0x142, 0xf, 0xf, true)));
    v = fmaxf(v, __int_as_float(__builtin_amdgcn_update_dpp(0, __float_as_int(v), 0x143, 0xf, 0xf, true)));
    return __int_as_float(__builtin_amdgcn_readlane(__float_as_int(v), 63));
}

// ---------------- K1: FPS (block 0) + KNN workers (blocks 1..255, waves 0..3) + heaters ----------------
// waves_per_eu(4,4): grid = 1 block/CU (16 waves = 4/SIMD) regardless; lowering the
// occupancy target raises the VGPR budget to 128 so gx/gy/gz[16] stay in registers
// (round 6: default 8-waves target forced a 64-VGPR cap -> scratch spill, +368MB WRITE_SIZE).
__global__ __launch_bounds__(1024) __attribute__((amdgpu_waves_per_eu(4, 4))) void k1_fps(
    const float* __restrict__ p,
    float* __restrict__ rx, float* __restrict__ ry, float* __restrict__ rz,
    int* __restrict__ rid,
    int* __restrict__ fidx, float* __restrict__ out, int* __restrict__ flag,
    const float* __restrict__ px, const float* __restrict__ py,
    const float* __restrict__ pz, const float* __restrict__ sump,
    int* __restrict__ knn)
{
    int tid = threadIdx.x, lane = tid & 63, wv = tid >> 6;

    __shared__ int hist[4096];
    __shared__ float sred[16][6];
    __shared__ int wsum[16];
    __shared__ float4 pool4[POOL_C];     // x,y,z,d
    __shared__ unsigned ppk[POOL_C];     // rid
    __shared__ float4 barr4[POOL_C+1];   // batch winner coords
    __shared__ unsigned skeys[POOL_C];   // batch winner rids (batched fidx publish)
    __shared__ float fdv[16];
    __shared__ unsigned fdk[16];
    __shared__ unsigned mcell;
    __shared__ float s_invm;
    __shared__ int s_cutbin;
    __shared__ unsigned s_cutbits;
    __shared__ unsigned s_fkey;
    __shared__ int bcnt, tcell;
    __shared__ float sdk[4][16][64];     // worker KNN merge (waves 0..3)
    __shared__ int   sik[4][16][64];

    if (blockIdx.x != 0) {
        // workers + heaters: keep chip busy (clocks) AND do KNN as fidx[q] becomes available
        float a0 = 1.0f + tid, a1 = 2.0f, a2 = 3.0f, a3 = 4.0f;
        const float hb = 1.0000001f, hc = 1e-9f;
        if (wv < 4) {
            int g = (blockIdx.x - 1) * 4 + wv;            // 0..1019
            for (int jq = 0; jq < 9; ++jq) {
                int q = g + 1020 * jq;
                if (q >= M_TOTAL) break;
                // wait until FPS produced fidx[q] (slot self-validating: != -1)
                int qi = -1;
                for (;;) {
                    if (lane == 0)
                        qi = __hip_atomic_load(&fidx[q], __ATOMIC_RELAXED, __HIP_MEMORY_SCOPE_AGENT);
                    qi = __shfl(qi, 0);
                    if (qi >= 0) break;
#pragma unroll
                    for (int u = 0; u < 256; ++u) {
                        a0 = __fmaf_rn(a0, hb, hc); a1 = __fmaf_rn(a1, hb, hc);
                        a2 = __fmaf_rn(a2, hb, hc); a3 = __fmaf_rn(a3, hb, hc);
                    }
                }
                // ---- KNN for query q (exact copy of old k2 body) ----
                float qx = px[qi], qy = py[qi], qz = pz[qi], sq = sump[qi];
                float bd[16]; int bi[16];
#pragma unroll
                for (int k = 0; k < 16; ++k) { bd[k] = 3.4e38f; bi[k] = 0x7fffffff; }
                for (int j0 = 0; j0 < N_PTS; j0 += 64) {
                    int j = j0 + lane;
                    float dot = __fmaf_rn(pz[j], qz, __fmaf_rn(py[j], qy, __fmul_rn(px[j], qx)));
                    float d = __fadd_rn(__fsub_rn(sq, __fmul_rn(2.0f, dot)), sump[j]);
                    if (d < bd[15]) {
                        float cdv = d; int ci = j;
#pragma unroll
                        for (int k = 0; k < 16; ++k) {
                            if (cdv < bd[k]) { float td = bd[k]; int ti = bi[k]; bd[k] = cdv; bi[k] = ci; cdv = td; ci = ti; }
                        }
                    }
                }
#pragma unroll
                for (int k = 0; k < 16; ++k) { sdk[wv][k][lane] = bd[k]; sik[wv][k][lane] = bi[k]; }
                int pos = 0;
                for (int r = 0; r < 16; ++r) {
                    float hd = (pos < 16) ? sdk[wv][pos][lane] : 3.4e38f;
                    int   hi2 = (pos < 16) ? sik[wv][pos][lane] : 0x7fffffff;
                    float md = hd; int mi = hi2;
#pragma unroll
                    for (int off = 1; off < 64; off <<= 1) {
                        float od = __shfl_xor(md, off);
                        int   oi = __shfl_xor(mi, off);
                        if (od < md || (od == md && oi < mi)) { md = od; mi = oi; }
                    }
                    if (hi2 == mi && pos < 16) pos++;
                    if (lane == 0) knn[q*16 + r] = mi;
                }
            }
        }
        // heater until FPS done
        for (;;) {
#pragma unroll
            for (int u = 0; u < 512; ++u) {
                a0 = __fmaf_rn(a0, hb, hc); a1 = __fmaf_rn(a1, hb, hc);
                a2 = __fmaf_rn(a2, hb, hc); a3 = __fmaf_rn(a3, hb, hc);
            }
            int done = 0;
            if (lane == 0)
                done = __hip_atomic_load(flag, __ATOMIC_RELAXED, __HIP_MEMORY_SCOPE_AGENT);
            done = __shfl(done, 0);
            if (done) break;
        }
        __asm__ volatile("" :: "v"(a0), "v"(a1), "v"(a2), "v"(a3));
        return;
    }

    // ======== Morton sort ========
    float mnx = 3.4e38f, mny = 3.4e38f, mnz = 3.4e38f;
    float mxx = -3.4e38f, mxy = -3.4e38f, mxz = -3.4e38f;
#pragma unroll
    for (int k = 0; k < 16; ++k) {
        int i = tid + 1024*k;
        float x = p[3*i], y = p[3*i+1], z = p[3*i+2];
        mnx = fminf(mnx, x); mxx = fmaxf(mxx, x);
        mny = fminf(mny, y); mxy = fmaxf(mxy, y);
        mnz = fminf(mnz, z); mxz = fmaxf(mxz, z);
    }
#pragma unroll
    for (int off = 1; off < 64; off <<= 1) {
        mnx = fminf(mnx, __shfl_xor(mnx, off)); mxx = fmaxf(mxx, __shfl_xor(mxx, off));
        mny = fminf(mny, __shfl_xor(mny, off)); mxy = fmaxf(mxy, __shfl_xor(mxy, off));
        mnz = fminf(mnz, __shfl_xor(mnz, off)); mxz = fmaxf(mxz, __shfl_xor(mxz, off));
    }
    if (lane == 0) {
        sred[wv][0] = mnx; sred[wv][1] = mxx; sred[wv][2] = mny;
        sred[wv][3] = mxy; sred[wv][4] = mnz; sred[wv][5] = mxz;
    }
    for (int j = tid; j < 4096; j += 1024) hist[j] = 0;
    __syncthreads();
    mnx = sred[0][0]; mxx = sred[0][1]; mny = sred[0][2];
    mxy = sred[0][3]; mnz = sred[0][4]; mxz = sred[0][5];
    for (int w2 = 1; w2 < 16; ++w2) {
        mnx = fminf(mnx, sred[w2][0]); mxx = fmaxf(mxx, sred[w2][1]);
        mny = fminf(mny, sred[w2][2]); mxy = fmaxf(mxy, sred[w2][3]);
        mnz = fminf(mnz, sred[w2][4]); mxz = fmaxf(mxz, sred[w2][5]);
    }
    float sx = 16.0f / fmaxf(mxx - mnx, 1e-20f);
    float sy = 16.0f / fmaxf(mxy - mny, 1e-20f);
    float sz = 16.0f / fmaxf(mxz - mnz, 1e-20f);

    int mcode[16];
#pragma unroll
    for (int k = 0; k < 16; ++k) {
        int i = tid + 1024*k;
        float x = p[3*i], y = p[3*i+1], z = p[3*i+2];
        int cx = min(15, (int)((x - mnx) * sx));
        int cy = min(15, (int)((y - mny) * sy));
        int cz = min(15, (int)((z - mnz) * sz));
        int m = (int)(spread4((unsigned)cx) | (spread4((unsigned)cy) << 1) | (spread4((unsigned)cz) << 2));
        mcode[k] = m;
        atomicAdd(&hist[m], 1);
    }
    __syncthreads();
    {
        int c0 = hist[4*tid], c1 = hist[4*tid+1], c2 = hist[4*tid+2], c3 = hist[4*tid+3];
        int lsum = c0 + c1 + c2 + c3;
        int incl = lsum;
#pragma unroll
        for (int off = 1; off < 64; off <<= 1) {
            int n = __shfl_up(incl, off);
            if (lane >= off) incl += n;
        }
        if (lane == 63) wsum[wv] = incl;
        __syncthreads();
        int woff = 0;
        for (int j = 0; j < wv; ++j) woff += wsum[j];
        int excl = woff + incl - lsum;
        hist[4*tid]   = excl;
        hist[4*tid+1] = excl + c0;
        hist[4*tid+2] = excl + c0 + c1;
        hist[4*tid+3] = excl + c0 + c1 + c2;
    }
    __syncthreads();
#pragma unroll
    for (int k = 0; k < 16; ++k) {
        int i = tid + 1024*k;
        int pos = atomicAdd(&hist[mcode[k]], 1);
        rx[pos] = p[3*i]; ry[pos] = p[3*i+1]; rz[pos] = p[3*i+2];
        rid[pos] = i;
    }
    __syncthreads();

    // ======== per-thread group state: coords REGISTER-RESIDENT (immutable after scatter) ========
    int base = tid * 16;
    float ld[16];
    float gx[16], gy[16], gz[16];
    float bmnx = 3.4e38f, bmny = 3.4e38f, bmnz = 3.4e38f;
    float bmxx = -3.4e38f, bmxy = -3.4e38f, bmxz = -3.4e38f;
#pragma unroll
    for (int k = 0; k < 16; ++k) {
        float x = rx[base+k], y = ry[base+k], z = rz[base+k];
        gx[k] = x; gy[k] = y; gz[k] = z;
        ld[k] = 1e10f;
        bmnx = fminf(bmnx, x); bmxx = fmaxf(bmxx, x);
        bmny = fminf(bmny, y); bmxy = fmaxf(bmxy, y);
        bmnz = fminf(bmnz, z); bmxz = fmaxf(bmxz, z);
    }
    float wsmnx = bmnx, wsmxx = bmxx, wsmny = bmny, wsmxy = bmxy, wsmnz = bmnz, wsmxz = bmxz;
#pragma unroll
    for (int off = 1; off < 64; off <<= 1) {
        wsmnx = fminf(wsmnx, __shfl_xor(wsmnx, off)); wsmxx = fmaxf(wsmxx, __shfl_xor(wsmxx, off));
        wsmny = fminf(wsmny, __shfl_xor(wsmny, off)); wsmxy = fmaxf(wsmxy, __shfl_xor(wsmxy, off));
        wsmnz = fminf(wsmnz, __shfl_xor(wsmnz, off)); wsmxz = fmaxf(wsmxz, __shfl_xor(wsmxz, off));
    }
    float gmax = 1e10f, wave_gmax = 1e10f;

    if (tid == 0) {
        float x0 = p[0], y0 = p[1], z0 = p[2];
        out[OUT_NP+0] = x0; out[OUT_NP+1] = y0; out[OUT_NP+2] = z0;
        barr4[0] = make_float4(x0, y0, z0, 0.0f);
        skeys[0] = 0u;
        bcnt = 1; tcell = 1; mcell = 0u;
    }

    // ======== main refresh loop ========
    for (;;) {
        __syncthreads();                                  // B1
        int t_now = tcell;
        int s = bcnt;
        // batched fidx publish of the batch that just finished selection: [t_now - s, t_now)
        if (tid < s)
            __hip_atomic_store(&fidx[t_now - s + tid], (int)skeys[tid], __ATOMIC_RELAXED, __HIP_MEMORY_SCOPE_AGENT);
        if (t_now >= M_TOTAL) break;

        // ---- apply batch (s <= 64: single ballot chunk); coords from registers ----
        {
            bool dirtyw = false;
            if (lane < s) {
                float4 cc = barr4[lane];
                dirtyw = bb_d2(cc.x, cc.y, cc.z, wsmnx, wsmxx, wsmny, wsmxy, wsmnz, wsmxz) < wave_gmax;
            }
            unsigned long long mm = __ballot(dirtyw);
            while (mm) {
                int b = __builtin_ctzll(mm); mm &= mm - 1;
                float4 cc = barr4[b];
                if (bb_d2(cc.x, cc.y, cc.z, bmnx, bmxx, bmny, bmxy, bmnz, bmxz) < gmax) {
#pragma unroll
                    for (int k = 0; k < 16; ++k)
                        ld[k] = fminf(ld[k], pt_d2(gx[k], gy[k], gz[k], cc.x, cc.y, cc.z));
                }
            }
        }
        gmax = ld[0];
#pragma unroll
        for (int k = 1; k < 16; ++k) gmax = fmaxf(gmax, ld[k]);
        wave_gmax = wave_max64(gmax);
        if (lane == 0) atomicMax(&mcell, __float_as_uint(wave_gmax));
        if (tid < 130) hist[tid] = 0;
        __syncthreads();                                  // B2
        if (tid == 0) { s_invm = 1.0f / __uint_as_float(mcell); mcell = 0u; }
        __syncthreads();                                  // B3
        float invm = s_invm;
        // filtered histogram: only r >= 0.5 (129 fine bins over [0.5, 1])
#pragma unroll
        for (int k = 0; k < 16; ++k) {
            unsigned u = __float_as_uint(__fmul_rn(ld[k], invm));
            if (u >= 0x3F000000u) {
                int bin = 16256 - (int)(u >> 16);
                bin = bin < 0 ? 0 : (bin > 128 ? 128 : bin);
                atomicAdd(&hist[bin], 1);
            }
        }
        __syncthreads();                                  // B4
        if (wv == 0) {
            int b0 = hist[2*lane], b1 = hist[2*lane+1];   // bins 0..127
            int pair = b0 + b1;
            int incl = pair;
#pragma unroll
            for (int off = 1; off < 64; off <<= 1) { int n = __shfl_up(incl, off); if (lane >= off) incl += n; }
            int before = incl - pair;
            int cb = 0;
            if (before + b0 <= POOL_C) cb = 2*lane + 1;
            if (before + pair <= POOL_C) cb = 2*lane + 2;
            if (lane == 63) { if (incl + hist[128] <= POOL_C) cb = 129; }
#pragma unroll
            for (int off = 1; off < 64; off <<= 1) cb = max(cb, __shfl_xor(cb, off));
            if (lane == 0) { s_cutbin = cb; s_cutbits = (unsigned)(16257 - cb) << 16; }
        }
        __syncthreads();                                  // B5

        // ---- compact-count (runs in degenerate case too; cheap) ----
        unsigned cutbits = s_cutbits;
        int cl = 0;
#pragma unroll
        for (int k = 0; k < 16; ++k)
            cl += (__float_as_uint(__fmul_rn(ld[k], invm)) >= cutbits) ? 1 : 0;
        int inc3 = cl;
#pragma unroll
        for (int off = 1; off < 64; off <<= 1) { int n = __shfl_up(inc3, off); if (lane >= off) inc3 += n; }
        if (lane == 63) wsum[wv] = inc3;
        __syncthreads();                                  // B6
        int woff2 = 0, ptot = 0;
        for (int j = 0; j < 16; ++j) { int wsj = wsum[j]; if (j < wv) woff2 += wsj; ptot += wsj; }

        if (s_cutbin == 0 || ptot == 0) {
            // degenerate / empty-pool guard: one exact full argmax step (guaranteed progress)
            float bv = -1.0f; unsigned bk = 0xffffffffu;
#pragma unroll
            for (int k = 0; k < 16; ++k) {
                unsigned kk = ((unsigned)rid[base+k] << 14) | (unsigned)(base + k);
                bool better = (ld[k] > bv) || (ld[k] == bv && kk < bk);
                bv = better ? ld[k] : bv; bk = better ? kk : bk;
            }
#pragma unroll
            for (int off = 1; off < 64; off <<= 1) {
                float ov = __shfl_xor(bv, off); unsigned ok = __shfl_xor(bk, off);
                bool better = (ov > bv) || (ov == bv && ok < bk);
                bv = better ? ov : bv; bk = better ? ok : bk;
            }
            if (lane == 0) { fdv[wv] = bv; fdk[wv] = bk; }
            __syncthreads();
            if (tid < 64) {
                float v2 = (tid < 16) ? fdv[tid] : -1.0f;
                unsigned k2v = (tid < 16) ? fdk[tid] : 0xffffffffu;
#pragma unroll
                for (int off = 1; off < 16; off <<= 1) {
                    float ov = __shfl_xor(v2, off); unsigned ok = __shfl_xor(k2v, off);
                    bool better = (ov > v2) || (ov == v2 && ok < k2v);
                    v2 = better ? ov : v2; k2v = better ? ok : k2v;
                }
                if (tid == 0) {
                    s_fkey = k2v;
                    int pos = (int)(k2v & 16383u);
                    __hip_atomic_store(&fidx[t_now], (int)(k2v >> 14), __ATOMIC_RELAXED, __HIP_MEMORY_SCOPE_AGENT);
                    float wx = rx[pos], wy = ry[pos], wz = rz[pos];
                    int o = (t_now < M1) ? (OUT_NP + 3*t_now) : (OUT_NP2 + 3*(t_now - M1));
                    out[o] = wx; out[o+1] = wy; out[o+2] = wz;
                    tcell = t_now + 1; bcnt = 0;
                }
            }
            __syncthreads();
            {
                int pos = (int)(s_fkey & 16383u);
                float wx = rx[pos], wy = ry[pos], wz = rz[pos];
                if (bb_d2(wx, wy, wz, bmnx, bmxx, bmny, bmxy, bmnz, bmxz) < gmax) {
#pragma unroll
                    for (int k = 0; k < 16; ++k)
                        ld[k] = fminf(ld[k], pt_d2(gx[k], gy[k], gz[k], wx, wy, wz));
                }
            }
            continue;
        }

        // ---- compact pool (<= 64 entries; same bit predicate as histogram) ----
        int nb = woff2 + inc3 - cl;
#pragma unroll
        for (int k = 0; k < 16; ++k) {
            if (__float_as_uint(__fmul_rn(ld[k], invm)) >= cutbits) {
                pool4[nb] = make_float4(gx[k], gy[k], gz[k], ld[k]);
                ppk[nb] = (unsigned)rid[base+k];
                nb++;
            }
        }
        if (tid >= ptot && tid < POOL_C) {
            pool4[tid] = make_float4(0.0f, 0.0f, 0.0f, 0.0f);   // dv=0: never selected (cut > 0)
            ppk[tid] = 0x7fffffffu;
        }
        __syncthreads();                                  // B7

        // ---- serial selection in wave 0: ONE pool entry per lane ----
        if (wv == 0) {
            __builtin_amdgcn_s_setprio(3);
            float4 e = pool4[lane];
            float ex = e.x, ey = e.y, ez = e.z, dv = e.w;
            unsigned key = ppk[lane];
            int tl = t_now, bc = 0;
            float mw = wave_max64(dv);
            while (__float_as_uint(__fmul_rn(mw, invm)) >= cutbits) {
                unsigned long long tie = __ballot(dv == mw);
                int wl;
                if (__popcll(tie) == 1) {
                    wl = (int)__builtin_ctzll(tie);
                } else {
                    unsigned kk = (dv == mw) ? key : 0xffffffffu;
#pragma unroll
                    for (int off = 1; off < 64; off <<= 1) kk = min(kk, (unsigned)__shfl_xor((int)kk, off));
                    tie = __ballot(dv == mw && key == kk);
                    wl = (int)__builtin_ctzll(tie);
                }
                float wx = __int_as_float(__builtin_amdgcn_readlane(__float_as_int(ex), wl));
                float wy = __int_as_float(__builtin_amdgcn_readlane(__float_as_int(ey), wl));
                float wz = __int_as_float(__builtin_amdgcn_readlane(__float_as_int(ez), wl));
                unsigned wk = (unsigned)__builtin_amdgcn_readlane((int)key, wl);
                if (lane == 0) {
                    skeys[bc] = wk;                      // staged; published at next refresh (off serial chain)
                    int o = (tl < M1) ? (OUT_NP + 3*tl) : (OUT_NP2 + 3*(tl - M1));
                    out[o] = wx; out[o+1] = wy; out[o+2] = wz;
                    barr4[bc] = make_float4(wx, wy, wz, 0.0f);
                }
                ++bc; ++tl;
                if (tl >= M_TOTAL) break;
                dv = fminf(dv, pt_d2(ex, ey, ez, wx, wy, wz));   // winner lane -> 0 (self)
                mw = wave_max64(dv);
            }
            __builtin_amdgcn_s_setprio(0);
            if (lane == 0) { bcnt = bc; tcell = tl; }
        }
    }

    if (tid == 0) atomicExch(flag, 1);   // release workers/heaters
}

// ---------------- K3: gather + linear + per-(q,c) max/min + f64 partial sums ----------------
__global__ __launch_bounds__(128) void k3_gemm(const float* __restrict__ p3, const float* __restrict__ xin,
                                               const float* __restrict__ W,
                                               const int* __restrict__ fidx, const int* __restrict__ knn,
                                               float* __restrict__ hmax, float* __restrict__ hmin,
                                               double* __restrict__ psum, double* __restrict__ psq) {
    __shared__ __align__(16) float feats[16][68];
    int c = threadIdx.x;
    int qbase = blockIdx.x * 16;
    float w[68];
#pragma unroll
    for (int j = 0; j < 67; ++j) w[j] = W[j*128 + c];
    w[67] = 0.0f;

    double s = 0.0, ss = 0.0;
    for (int qq = 0; qq < 16; ++qq) {
        int q = qbase + qq;
        int qi = fidx[q];
        float qx = p3[3*qi], qy = p3[3*qi+1], qz = p3[3*qi+2];
        for (int i = c; i < 16*68; i += 128) {
            int sIdx = i / 68, j = i - sIdx*68;
            int nj = knn[q*16 + sIdx];
            float v;
            if (j < 3) {
                float pc = p3[3*nj + j];
                float qc = (j == 0) ? qx : ((j == 1) ? qy : qz);
                v = pc - qc;
            } else if (j < 67) {
                v = xin[nj*64 + (j-3)];
            } else v = 0.0f;
            feats[sIdx][j] = v;
        }
        __syncthreads();
        float hmx = -3.4e38f, hmn = 3.4e38f;
        for (int sIdx = 0; sIdx < 16; ++sIdx) {
            float acc = 0.0f;
#pragma unroll
            for (int mm = 0; mm < 17; ++mm) {
                float4 f = *(const float4*)&feats[sIdx][4*mm];
                acc = __fmaf_rn(f.x, w[4*mm+0], acc);
                acc = __fmaf_rn(f.y, w[4*mm+1], acc);
                acc = __fmaf_rn(f.z, w[4*mm+2], acc);
                acc = __fmaf_rn(f.w, w[4*mm+3], acc);
            }
            hmx = fmaxf(hmx, acc); hmn = fminf(hmn, acc);
            s += (double)acc; ss += (double)acc * (double)acc;
        }
        hmax[q*128 + c] = hmx; hmin[q*128 + c] = hmn;
        __syncthreads();
    }
    psum[blockIdx.x*128 + c] = s;
    psq [blockIdx.x*128 + c] = ss;
}

// ---------------- K3.5: BN stats -> per-channel scale/shift ----------------
__global__ void k35_stats(const double* __restrict__ psum, const double* __restrict__ psq,
                          const float* __restrict__ gamma, const float* __restrict__ beta,
                          float* __restrict__ scale, float* __restrict__ shift) {
    int t = threadIdx.x;
    int half = t >> 7, c = t & 127;
    double s = 0.0, ss = 0.0;
    for (int b = 0; b < 256; ++b) {
        int ib = (half*256 + b)*128 + c;
        s += psum[ib]; ss += psq[ib];
    }
    double mean = s / 65536.0;
    double var  = ss / 65536.0 - mean*mean;
    double sc   = (double)gamma[c] / sqrt(var + 1e-5);
    scale[t] = (float)sc;
    shift[t] = (float)((double)beta[c] - mean*sc);
}

// ---------------- K4: affine + relu on max/min -> x1/x2 ----------------
__global__ __launch_bounds__(256) void k4_out(const float* __restrict__ hmax, const float* __restrict__ hmin,
                                              const float* __restrict__ scale, const float* __restrict__ shift,
                                              float* __restrict__ out) {
    int e = blockIdx.x * 256 + threadIdx.x;
    int q = e >> 7, c = e & 127;
    int half = (q >= M1) ? 1 : 0;
    float a = scale[half*128 + c], b = shift[half*128 + c];
    float v = (a >= 0.0f) ? hmax[e] : hmin[e];
    float r = fmaxf(0.0f, a*v + b);
    int off = half ? (OUT_X2 + (q - M1)*128 + c) : (OUT_X1 + q*128 + c);
    out[off] = r;
}

extern "C" void kernel_launch(void* const* d_in, const int* in_sizes, int n_in,
                              void* d_out, int out_size, void* d_ws, size_t ws_size,
                              hipStream_t stream) {
    const float* p     = (const float*)d_in[0];
    const float* x     = (const float*)d_in[1];
    const float* W     = (const float*)d_in[3];
    const float* gamma = (const float*)d_in[4];
    const float* beta  = (const float*)d_in[5];
    float* out = (float*)d_out;

    float* wsf  = (float*)d_ws;
    float* sump = wsf;                 // 16384
    float* px   = wsf + 16384;
    float* py   = wsf + 32768;
    float* pz   = wsf + 49152;
    int*   fidx = (int*)(wsf + 65536); // 8192
    int*   knn  = (int*)(wsf + 73728); // 131072
    float* hmax = wsf + 204800;        // 1048576
    float* hmin = wsf + 1253376;       // 1048576
    // k1 scratch overlaid on hmax region (dead before k3 writes hmax)
    float* rxp  = hmax;                // 16384
    float* ryp  = hmax + 16384;
    float* rzp  = hmax + 32768;
    int*   ridp = (int*)(hmax + 49152);
    int*   flag = (int*)(wsf + 270336); // inside hmax region, past rid; dead before k3
    double* psum = (double*)((char*)d_ws + 9207808);
    double* psq  = psum + 65536;
    float* scale = (float*)(psq + 65536);
    float* shift = scale + 256;

    k0_init <<<64,   256, 0, stream>>>(p, sump, px, py, pz, out, flag, fidx);
    k1_fps  <<<256, 1024, 0, stream>>>(p, rxp, ryp, rzp, ridp, fidx, out, flag, px, py, pz, sump, knn);
    k3_gemm <<<512,  128, 0, stream>>>(p, x, W, fidx, knn, hmax, hmin, psum, psq);
    k35_stats<<<1,   256, 0, stream>>>(psum, psq, gamma, beta, scale, shift);
    k4_out  <<<4096, 256, 0, stream>>>(hmax, hmin, scale, shift, out);
}

// Round 8
// 5505.208 us; speedup vs baseline: 1.0478x; 1.0478x over previous
//
#include <hip/hip_runtime.h>

#define N_PTS 16384
#define M_TOTAL 8192
#define M1 4096

// output offsets (floats)
#define OUT_NP   0
#define OUT_X1   12288
#define OUT_NO   536576
#define OUT_NP2  536577
#define OUT_X2   548865
#define OUT_NO2  1073153

#define POOL_C 64

// ---------------- K0: |p|^2, SoA copy, n_o outputs, flag + fidx init ----------------
__global__ void k0_init(const float* __restrict__ p, float* __restrict__ sump,
                        float* __restrict__ px, float* __restrict__ py, float* __restrict__ pz,
                        float* __restrict__ out, int* __restrict__ flag, int* __restrict__ fidx) {
    int i = blockIdx.x * 256 + threadIdx.x;
    if (i == 0) { out[OUT_NO] = 4096.0f; out[OUT_NO2] = 4096.0f; atomicExch(flag, 0); }
    if (i < M_TOTAL) fidx[i] = (i == 0) ? 0 : -1;   // -1 = not yet produced (worker handshake)
    if (i < N_PTS) {
        float x = p[3*i], y = p[3*i+1], z = p[3*i+2];
        px[i] = x; py[i] = y; pz[i] = z;
        sump[i] = __fadd_rn(__fadd_rn(__fmul_rn(x,x), __fmul_rn(y,y)), __fmul_rn(z,z));
    }
}

__device__ __forceinline__ unsigned spread4(unsigned v) {
    return (v & 1u) | ((v & 2u) << 2) | ((v & 4u) << 4) | ((v & 8u) << 6);
}
// exact lower bound: rn ops, monotone rounding => d2bb <= d2(p,q) for p in bbox
__device__ __forceinline__ float bb_d2(float qx, float qy, float qz,
                                       float mnx, float mxx, float mny, float mxy,
                                       float mnz, float mxz) {
    float ax = fmaxf(fmaxf(__fsub_rn(mnx, qx), __fsub_rn(qx, mxx)), 0.0f);
    float ay = fmaxf(fmaxf(__fsub_rn(mny, qy), __fsub_rn(qy, mxy)), 0.0f);
    float az = fmaxf(fmaxf(__fsub_rn(mnz, qz), __fsub_rn(qz, mxz)), 0.0f);
    return __fadd_rn(__fadd_rn(__fmul_rn(ax,ax), __fmul_rn(ay,ay)), __fmul_rn(az,az));
}
// exact np replication: (dx*dx + dy*dy) + dz*dz, rn, no FMA
__device__ __forceinline__ float pt_d2(float ax, float ay, float az,
                                       float bx, float by, float bz) {
    float dx = __fsub_rn(ax,bx), dy = __fsub_rn(ay,by), dz = __fsub_rn(az,bz);
    return __fadd_rn(__fadd_rn(__fmul_rn(dx,dx), __fmul_rn(dy,dy)), __fmul_rn(dz,dz));
}
// wave64 max via DPP (row_shr 1,2,4,8 ; row_bcast15 ; row_bcast31), broadcast from lane63
__device__ __forceinline__ float wave_max64(float v) {
    v = fmaxf(v, __int_as_float(__builtin_amdgcn_update_dpp(0, __float_as_int(v), 0x111, 0xf, 0xf, true)));
    v = fmaxf(v, __int_as_float(__builtin_amdgcn_update_dpp(0, __float_as_int(v), 0x112, 0xf, 0xf, true)));
    v = fmaxf(v, __int_as_float(__builtin_amdgcn_update_dpp(0, __float_as_int(v), 0x114, 0xf, 0xf, true)));
    v = fmaxf(v, __int_as_float(__builtin_amdgcn_update_dpp(0, __float_as_int(v), 0x118, 0xf, 0xf, true)));
    v = fmaxf(v, __int_as_float(__builtin_amdgcn_update_dpp(0, __float_as_int(v), 0x142, 0xf, 0xf, true)));
    v = fmaxf(v, __int_as_float(__builtin_amdgcn_update_dpp(0, __float_as_int(v), 0x143, 0xf, 0xf, true)));
    return __int_as_float(__builtin_amdgcn_readlane(__float_as_int(v), 63));
}

// ---------------- K1: FPS (block 0) + KNN workers (blocks 1..255, waves 0..3) + heaters ----------------
// __launch_bounds__(1024, 4): second arg = min waves per EU (HIP semantics) -> VGPR budget 128.
// Grid is 1 block/CU (16 waves = 4/SIMD) either way, so occupancy is unchanged; this only
// stops the 64-VGPR-cap scratch spill (worker bd/bi top-k state + apply-phase coord arrays).
__global__ __launch_bounds__(1024, 4) void k1_fps(
    const float* __restrict__ p,
    float* __restrict__ rx, float* __restrict__ ry, float* __restrict__ rz,
    int* __restrict__ rid,
    int* __restrict__ fidx, float* __restrict__ out, int* __restrict__ flag,
    const float* __restrict__ px, const float* __restrict__ py,
    const float* __restrict__ pz, const float* __restrict__ sump,
    int* __restrict__ knn)
{
    int tid = threadIdx.x, lane = tid & 63, wv = tid >> 6;

    __shared__ int hist[4096];
    __shared__ float sred[16][6];
    __shared__ int wsum[16];
    __shared__ float4 pool4[POOL_C];     // x,y,z,d
    __shared__ unsigned ppk[POOL_C];     // rid
    __shared__ float4 barr4[POOL_C+1];   // batch winner coords
    __shared__ unsigned skeys[POOL_C];   // batch winner rids (batched fidx publish)
    __shared__ float fdv[16];
    __shared__ unsigned fdk[16];
    __shared__ unsigned mcell;
    __shared__ float s_invm;
    __shared__ int s_cutbin;
    __shared__ unsigned s_cutbits;
    __shared__ unsigned s_fkey;
    __shared__ int bcnt, tcell;
    __shared__ float sdk[4][16][64];     // worker KNN merge (waves 0..3)
    __shared__ int   sik[4][16][64];

    if (blockIdx.x != 0) {
        // workers + heaters: keep chip busy (clocks) AND do KNN as fidx[q] becomes available
        float a0 = 1.0f + tid, a1 = 2.0f, a2 = 3.0f, a3 = 4.0f;
        const float hb = 1.0000001f, hc = 1e-9f;
        if (wv < 4) {
            int g = (blockIdx.x - 1) * 4 + wv;            // 0..1019
            for (int jq = 0; jq < 9; ++jq) {
                int q = g + 1020 * jq;
                if (q >= M_TOTAL) break;
                // wait until FPS produced fidx[q] (slot self-validating: != -1)
                int qi = -1;
                for (;;) {
                    if (lane == 0)
                        qi = __hip_atomic_load(&fidx[q], __ATOMIC_RELAXED, __HIP_MEMORY_SCOPE_AGENT);
                    qi = __shfl(qi, 0);
                    if (qi >= 0) break;
#pragma unroll
                    for (int u = 0; u < 256; ++u) {
                        a0 = __fmaf_rn(a0, hb, hc); a1 = __fmaf_rn(a1, hb, hc);
                        a2 = __fmaf_rn(a2, hb, hc); a3 = __fmaf_rn(a3, hb, hc);
                    }
                }
                // ---- KNN for query q (exact copy of old k2 body) ----
                float qx = px[qi], qy = py[qi], qz = pz[qi], sq = sump[qi];
                float bd[16]; int bi[16];
#pragma unroll
                for (int k = 0; k < 16; ++k) { bd[k] = 3.4e38f; bi[k] = 0x7fffffff; }
                for (int j0 = 0; j0 < N_PTS; j0 += 64) {
                    int j = j0 + lane;
                    float dot = __fmaf_rn(pz[j], qz, __fmaf_rn(py[j], qy, __fmul_rn(px[j], qx)));
                    float d = __fadd_rn(__fsub_rn(sq, __fmul_rn(2.0f, dot)), sump[j]);
                    if (d < bd[15]) {
                        float cdv = d; int ci = j;
#pragma unroll
                        for (int k = 0; k < 16; ++k) {
                            if (cdv < bd[k]) { float td = bd[k]; int ti = bi[k]; bd[k] = cdv; bi[k] = ci; cdv = td; ci = ti; }
                        }
                    }
                }
#pragma unroll
                for (int k = 0; k < 16; ++k) { sdk[wv][k][lane] = bd[k]; sik[wv][k][lane] = bi[k]; }
                int pos = 0;
                for (int r = 0; r < 16; ++r) {
                    float hd = (pos < 16) ? sdk[wv][pos][lane] : 3.4e38f;
                    int   hi2 = (pos < 16) ? sik[wv][pos][lane] : 0x7fffffff;
                    float md = hd; int mi = hi2;
#pragma unroll
                    for (int off = 1; off < 64; off <<= 1) {
                        float od = __shfl_xor(md, off);
                        int   oi = __shfl_xor(mi, off);
                        if (od < md || (od == md && oi < mi)) { md = od; mi = oi; }
                    }
                    if (hi2 == mi && pos < 16) pos++;
                    if (lane == 0) knn[q*16 + r] = mi;
                }
            }
        }
        // heater until FPS done
        for (;;) {
#pragma unroll
            for (int u = 0; u < 512; ++u) {
                a0 = __fmaf_rn(a0, hb, hc); a1 = __fmaf_rn(a1, hb, hc);
                a2 = __fmaf_rn(a2, hb, hc); a3 = __fmaf_rn(a3, hb, hc);
            }
            int done = 0;
            if (lane == 0)
                done = __hip_atomic_load(flag, __ATOMIC_RELAXED, __HIP_MEMORY_SCOPE_AGENT);
            done = __shfl(done, 0);
            if (done) break;
        }
        __asm__ volatile("" :: "v"(a0), "v"(a1), "v"(a2), "v"(a3));
        return;
    }

    // ======== Morton sort ========
    float mnx = 3.4e38f, mny = 3.4e38f, mnz = 3.4e38f;
    float mxx = -3.4e38f, mxy = -3.4e38f, mxz = -3.4e38f;
#pragma unroll
    for (int k = 0; k < 16; ++k) {
        int i = tid + 1024*k;
        float x = p[3*i], y = p[3*i+1], z = p[3*i+2];
        mnx = fminf(mnx, x); mxx = fmaxf(mxx, x);
        mny = fminf(mny, y); mxy = fmaxf(mxy, y);
        mnz = fminf(mnz, z); mxz = fmaxf(mxz, z);
    }
#pragma unroll
    for (int off = 1; off < 64; off <<= 1) {
        mnx = fminf(mnx, __shfl_xor(mnx, off)); mxx = fmaxf(mxx, __shfl_xor(mxx, off));
        mny = fminf(mny, __shfl_xor(mny, off)); mxy = fmaxf(mxy, __shfl_xor(mxy, off));
        mnz = fminf(mnz, __shfl_xor(mnz, off)); mxz = fmaxf(mxz, __shfl_xor(mxz, off));
    }
    if (lane == 0) {
        sred[wv][0] = mnx; sred[wv][1] = mxx; sred[wv][2] = mny;
        sred[wv][3] = mxy; sred[wv][4] = mnz; sred[wv][5] = mxz;
    }
    for (int j = tid; j < 4096; j += 1024) hist[j] = 0;
    __syncthreads();
    mnx = sred[0][0]; mxx = sred[0][1]; mny = sred[0][2];
    mxy = sred[0][3]; mnz = sred[0][4]; mxz = sred[0][5];
    for (int w2 = 1; w2 < 16; ++w2) {
        mnx = fminf(mnx, sred[w2][0]); mxx = fmaxf(mxx, sred[w2][1]);
        mny = fminf(mny, sred[w2][2]); mxy = fmaxf(mxy, sred[w2][3]);
        mnz = fminf(mnz, sred[w2][4]); mxz = fmaxf(mxz, sred[w2][5]);
    }
    float sx = 16.0f / fmaxf(mxx - mnx, 1e-20f);
    float sy = 16.0f / fmaxf(mxy - mny, 1e-20f);
    float sz = 16.0f / fmaxf(mxz - mnz, 1e-20f);

    int mcode[16];
#pragma unroll
    for (int k = 0; k < 16; ++k) {
        int i = tid + 1024*k;
        float x = p[3*i], y = p[3*i+1], z = p[3*i+2];
        int cx = min(15, (int)((x - mnx) * sx));
        int cy = min(15, (int)((y - mny) * sy));
        int cz = min(15, (int)((z - mnz) * sz));
        int m = (int)(spread4((unsigned)cx) | (spread4((unsigned)cy) << 1) | (spread4((unsigned)cz) << 2));
        mcode[k] = m;
        atomicAdd(&hist[m], 1);
    }
    __syncthreads();
    {
        int c0 = hist[4*tid], c1 = hist[4*tid+1], c2 = hist[4*tid+2], c3 = hist[4*tid+3];
        int lsum = c0 + c1 + c2 + c3;
        int incl = lsum;
#pragma unroll
        for (int off = 1; off < 64; off <<= 1) {
            int n = __shfl_up(incl, off);
            if (lane >= off) incl += n;
        }
        if (lane == 63) wsum[wv] = incl;
        __syncthreads();
        int woff = 0;
        for (int j = 0; j < wv; ++j) woff += wsum[j];
        int excl = woff + incl - lsum;
        hist[4*tid]   = excl;
        hist[4*tid+1] = excl + c0;
        hist[4*tid+2] = excl + c0 + c1;
        hist[4*tid+3] = excl + c0 + c1 + c2;
    }
    __syncthreads();
#pragma unroll
    for (int k = 0; k < 16; ++k) {
        int i = tid + 1024*k;
        int pos = atomicAdd(&hist[mcode[k]], 1);
        rx[pos] = p[3*i]; ry[pos] = p[3*i+1]; rz[pos] = p[3*i+2];
        rid[pos] = i;
    }
    __syncthreads();

    // ======== per-thread group state ========
    int base = tid * 16;
    float ld[16];
    float bmnx = 3.4e38f, bmny = 3.4e38f, bmnz = 3.4e38f;
    float bmxx = -3.4e38f, bmxy = -3.4e38f, bmxz = -3.4e38f;
#pragma unroll
    for (int k = 0; k < 16; ++k) {
        float x = rx[base+k], y = ry[base+k], z = rz[base+k];
        ld[k] = 1e10f;
        bmnx = fminf(bmnx, x); bmxx = fmaxf(bmxx, x);
        bmny = fminf(bmny, y); bmxy = fmaxf(bmxy, y);
        bmnz = fminf(bmnz, z); bmxz = fmaxf(bmxz, z);
    }
    float wsmnx = bmnx, wsmxx = bmxx, wsmny = bmny, wsmxy = bmxy, wsmnz = bmnz, wsmxz = bmxz;
#pragma unroll
    for (int off = 1; off < 64; off <<= 1) {
        wsmnx = fminf(wsmnx, __shfl_xor(wsmnx, off)); wsmxx = fmaxf(wsmxx, __shfl_xor(wsmxx, off));
        wsmny = fminf(wsmny, __shfl_xor(wsmny, off)); wsmxy = fmaxf(wsmxy, __shfl_xor(wsmxy, off));
        wsmnz = fminf(wsmnz, __shfl_xor(wsmnz, off)); wsmxz = fmaxf(wsmxz, __shfl_xor(wsmxz, off));
    }
    float gmax = 1e10f, wave_gmax = 1e10f;

    if (tid == 0) {
        float x0 = p[0], y0 = p[1], z0 = p[2];
        out[OUT_NP+0] = x0; out[OUT_NP+1] = y0; out[OUT_NP+2] = z0;
        barr4[0] = make_float4(x0, y0, z0, 0.0f);
        skeys[0] = 0u;
        bcnt = 1; tcell = 1; mcell = 0u;
    }

    // ======== main refresh loop ========
    for (;;) {
        __syncthreads();                                  // B1
        int t_now = tcell;
        int s = bcnt;
        // batched fidx publish of the batch that just finished selection: [t_now - s, t_now)
        if (tid < s)
            __hip_atomic_store(&fidx[t_now - s + tid], (int)skeys[tid], __ATOMIC_RELAXED, __HIP_MEMORY_SCOPE_AGENT);
        if (t_now >= M_TOTAL) break;

        // ---- apply batch (s <= 64: single ballot chunk); lazy coord load for dirty waves ----
        {
            bool dirtyw = false;
            if (lane < s) {
                float4 cc = barr4[lane];
                dirtyw = bb_d2(cc.x, cc.y, cc.z, wsmnx, wsmxx, wsmny, wsmxy, wsmnz, wsmxz) < wave_gmax;
            }
            unsigned long long mm = __ballot(dirtyw);
            if (mm) {
                float gx[16], gy[16], gz[16];
#pragma unroll
                for (int k = 0; k < 16; ++k) { gx[k] = rx[base+k]; gy[k] = ry[base+k]; gz[k] = rz[base+k]; }
                while (mm) {
                    int b = __builtin_ctzll(mm); mm &= mm - 1;
                    float4 cc = barr4[b];
                    if (bb_d2(cc.x, cc.y, cc.z, bmnx, bmxx, bmny, bmxy, bmnz, bmxz) < gmax) {
#pragma unroll
                        for (int k = 0; k < 16; ++k)
                            ld[k] = fminf(ld[k], pt_d2(gx[k], gy[k], gz[k], cc.x, cc.y, cc.z));
                    }
                }
            }
        }
        gmax = ld[0];
#pragma unroll
        for (int k = 1; k < 16; ++k) gmax = fmaxf(gmax, ld[k]);
        wave_gmax = wave_max64(gmax);
        if (lane == 0) atomicMax(&mcell, __float_as_uint(wave_gmax));
        if (tid < 130) hist[tid] = 0;
        __syncthreads();                                  // B2
        if (tid == 0) { s_invm = 1.0f / __uint_as_float(mcell); mcell = 0u; }
        __syncthreads();                                  // B3
        float invm = s_invm;
        // filtered histogram: only r >= 0.5 (129 fine bins over [0.5, 1])
#pragma unroll
        for (int k = 0; k < 16; ++k) {
            unsigned u = __float_as_uint(__fmul_rn(ld[k], invm));
            if (u >= 0x3F000000u) {
                int bin = 16256 - (int)(u >> 16);
                bin = bin < 0 ? 0 : (bin > 128 ? 128 : bin);
                atomicAdd(&hist[bin], 1);
            }
        }
        __syncthreads();                                  // B4
        if (wv == 0) {
            int b0 = hist[2*lane], b1 = hist[2*lane+1];   // bins 0..127
            int pair = b0 + b1;
            int incl = pair;
#pragma unroll
            for (int off = 1; off < 64; off <<= 1) { int n = __shfl_up(incl, off); if (lane >= off) incl += n; }
            int before = incl - pair;
            int cb = 0;
            if (before + b0 <= POOL_C) cb = 2*lane + 1;
            if (before + pair <= POOL_C) cb = 2*lane + 2;
            if (lane == 63) { if (incl + hist[128] <= POOL_C) cb = 129; }
#pragma unroll
            for (int off = 1; off < 64; off <<= 1) cb = max(cb, __shfl_xor(cb, off));
            if (lane == 0) { s_cutbin = cb; s_cutbits = (unsigned)(16257 - cb) << 16; }
        }
        __syncthreads();                                  // B5

        // ---- compact-count (runs in degenerate case too; cheap) ----
        unsigned cutbits = s_cutbits;
        int cl = 0;
#pragma unroll
        for (int k = 0; k < 16; ++k)
            cl += (__float_as_uint(__fmul_rn(ld[k], invm)) >= cutbits) ? 1 : 0;
        int inc3 = cl;
#pragma unroll
        for (int off = 1; off < 64; off <<= 1) { int n = __shfl_up(inc3, off); if (lane >= off) inc3 += n; }
        if (lane == 63) wsum[wv] = inc3;
        __syncthreads();                                  // B6
        int woff2 = 0, ptot = 0;
        for (int j = 0; j < 16; ++j) { int wsj = wsum[j]; if (j < wv) woff2 += wsj; ptot += wsj; }

        if (s_cutbin == 0 || ptot == 0) {
            // degenerate / empty-pool guard: one exact full argmax step (guaranteed progress)
            float bv = -1.0f; unsigned bk = 0xffffffffu;
#pragma unroll
            for (int k = 0; k < 16; ++k) {
                unsigned kk = ((unsigned)rid[base+k] << 14) | (unsigned)(base + k);
                bool better = (ld[k] > bv) || (ld[k] == bv && kk < bk);
                bv = better ? ld[k] : bv; bk = better ? kk : bk;
            }
#pragma unroll
            for (int off = 1; off < 64; off <<= 1) {
                float ov = __shfl_xor(bv, off); unsigned ok = __shfl_xor(bk, off);
                bool better = (ov > bv) || (ov == bv && ok < bk);
                bv = better ? ov : bv; bk = better ? ok : bk;
            }
            if (lane == 0) { fdv[wv] = bv; fdk[wv] = bk; }
            __syncthreads();
            if (tid < 64) {
                float v2 = (tid < 16) ? fdv[tid] : -1.0f;
                unsigned k2v = (tid < 16) ? fdk[tid] : 0xffffffffu;
#pragma unroll
                for (int off = 1; off < 16; off <<= 1) {
                    float ov = __shfl_xor(v2, off); unsigned ok = __shfl_xor(k2v, off);
                    bool better = (ov > v2) || (ov == v2 && ok < k2v);
                    v2 = better ? ov : v2; k2v = better ? ok : k2v;
                }
                if (tid == 0) {
                    s_fkey = k2v;
                    int pos = (int)(k2v & 16383u);
                    __hip_atomic_store(&fidx[t_now], (int)(k2v >> 14), __ATOMIC_RELAXED, __HIP_MEMORY_SCOPE_AGENT);
                    float wx = rx[pos], wy = ry[pos], wz = rz[pos];
                    int o = (t_now < M1) ? (OUT_NP + 3*t_now) : (OUT_NP2 + 3*(t_now - M1));
                    out[o] = wx; out[o+1] = wy; out[o+2] = wz;
                    tcell = t_now + 1; bcnt = 0;
                }
            }
            __syncthreads();
            {
                int pos = (int)(s_fkey & 16383u);
                float wx = rx[pos], wy = ry[pos], wz = rz[pos];
                if (bb_d2(wx, wy, wz, bmnx, bmxx, bmny, bmxy, bmnz, bmxz) < gmax) {
#pragma unroll
                    for (int k = 0; k < 16; ++k)
                        ld[k] = fminf(ld[k], pt_d2(rx[base+k], ry[base+k], rz[base+k], wx, wy, wz));
                }
            }
            continue;
        }

        // ---- compact pool (<= 64 entries; same bit predicate as histogram) ----
        int nb = woff2 + inc3 - cl;
#pragma unroll
        for (int k = 0; k < 16; ++k) {
            if (__float_as_uint(__fmul_rn(ld[k], invm)) >= cutbits) {
                pool4[nb] = make_float4(rx[base+k], ry[base+k], rz[base+k], ld[k]);
                ppk[nb] = (unsigned)rid[base+k];
                nb++;
            }
        }
        if (tid >= ptot && tid < POOL_C) {
            pool4[tid] = make_float4(0.0f, 0.0f, 0.0f, 0.0f);   // dv=0: never selected (cut > 0)
            ppk[tid] = 0x7fffffffu;
        }
        __syncthreads();                                  // B7

        // ---- serial selection in wave 0: ONE pool entry per lane ----
        if (wv == 0) {
            __builtin_amdgcn_s_setprio(3);
            float4 e = pool4[lane];
            float ex = e.x, ey = e.y, ez = e.z, dv = e.w;
            unsigned key = ppk[lane];
            int tl = t_now, bc = 0;
            float mw = wave_max64(dv);
            while (__float_as_uint(__fmul_rn(mw, invm)) >= cutbits) {
                unsigned long long tie = __ballot(dv == mw);
                int wl;
                if (__popcll(tie) == 1) {
                    wl = (int)__builtin_ctzll(tie);
                } else {
                    unsigned kk = (dv == mw) ? key : 0xffffffffu;
#pragma unroll
                    for (int off = 1; off < 64; off <<= 1) kk = min(kk, (unsigned)__shfl_xor((int)kk, off));
                    tie = __ballot(dv == mw && key == kk);
                    wl = (int)__builtin_ctzll(tie);
                }
                float wx = __int_as_float(__builtin_amdgcn_readlane(__float_as_int(ex), wl));
                float wy = __int_as_float(__builtin_amdgcn_readlane(__float_as_int(ey), wl));
                float wz = __int_as_float(__builtin_amdgcn_readlane(__float_as_int(ez), wl));
                unsigned wk = (unsigned)__builtin_amdgcn_readlane((int)key, wl);
                if (lane == 0) {
                    skeys[bc] = wk;                      // staged; published at next refresh (off serial chain)
                    int o = (tl < M1) ? (OUT_NP + 3*tl) : (OUT_NP2 + 3*(tl - M1));
                    out[o] = wx; out[o+1] = wy; out[o+2] = wz;
                    barr4[bc] = make_float4(wx, wy, wz, 0.0f);
                }
                ++bc; ++tl;
                if (tl >= M_TOTAL) break;
                dv = fminf(dv, pt_d2(ex, ey, ez, wx, wy, wz));   // winner lane -> 0 (self)
                mw = wave_max64(dv);
            }
            __builtin_amdgcn_s_setprio(0);
            if (lane == 0) { bcnt = bc; tcell = tl; }
        }
    }

    if (tid == 0) atomicExch(flag, 1);   // release workers/heaters
}

// ---------------- K3: gather + linear + per-(q,c) max/min + f64 partial sums ----------------
__global__ __launch_bounds__(128) void k3_gemm(const float* __restrict__ p3, const float* __restrict__ xin,
                                               const float* __restrict__ W,
                                               const int* __restrict__ fidx, const int* __restrict__ knn,
                                               float* __restrict__ hmax, float* __restrict__ hmin,
                                               double* __restrict__ psum, double* __restrict__ psq) {
    __shared__ __align__(16) float feats[16][68];
    int c = threadIdx.x;
    int qbase = blockIdx.x * 16;
    float w[68];
#pragma unroll
    for (int j = 0; j < 67; ++j) w[j] = W[j*128 + c];
    w[67] = 0.0f;

    double s = 0.0, ss = 0.0;
    for (int qq = 0; qq < 16; ++qq) {
        int q = qbase + qq;
        int qi = fidx[q];
        float qx = p3[3*qi], qy = p3[3*qi+1], qz = p3[3*qi+2];
        for (int i = c; i < 16*68; i += 128) {
            int sIdx = i / 68, j = i - sIdx*68;
            int nj = knn[q*16 + sIdx];
            float v;
            if (j < 3) {
                float pc = p3[3*nj + j];
                float qc = (j == 0) ? qx : ((j == 1) ? qy : qz);
                v = pc - qc;
            } else if (j < 67) {
                v = xin[nj*64 + (j-3)];
            } else v = 0.0f;
            feats[sIdx][j] = v;
        }
        __syncthreads();
        float hmx = -3.4e38f, hmn = 3.4e38f;
        for (int sIdx = 0; sIdx < 16; ++sIdx) {
            float acc = 0.0f;
#pragma unroll
            for (int mm = 0; mm < 17; ++mm) {
                float4 f = *(const float4*)&feats[sIdx][4*mm];
                acc = __fmaf_rn(f.x, w[4*mm+0], acc);
                acc = __fmaf_rn(f.y, w[4*mm+1], acc);
                acc = __fmaf_rn(f.z, w[4*mm+2], acc);
                acc = __fmaf_rn(f.w, w[4*mm+3], acc);
            }
            hmx = fmaxf(hmx, acc); hmn = fminf(hmn, acc);
            s += (double)acc; ss += (double)acc * (double)acc;
        }
        hmax[q*128 + c] = hmx; hmin[q*128 + c] = hmn;
        __syncthreads();
    }
    psum[blockIdx.x*128 + c] = s;
    psq [blockIdx.x*128 + c] = ss;
}

// ---------------- K3.5: BN stats -> per-channel scale/shift ----------------
__global__ void k35_stats(const double* __restrict__ psum, const double* __restrict__ psq,
                          const float* __restrict__ gamma, const float* __restrict__ beta,
                          float* __restrict__ scale, float* __restrict__ shift) {
    int t = threadIdx.x;
    int half = t >> 7, c = t & 127;
    double s = 0.0, ss = 0.0;
    for (int b = 0; b < 256; ++b) {
        int ib = (half*256 + b)*128 + c;
        s += psum[ib]; ss += psq[ib];
    }
    double mean = s / 65536.0;
    double var  = ss / 65536.0 - mean*mean;
    double sc   = (double)gamma[c] / sqrt(var + 1e-5);
    scale[t] = (float)sc;
    shift[t] = (float)((double)beta[c] - mean*sc);
}

// ---------------- K4: affine + relu on max/min -> x1/x2 ----------------
__global__ __launch_bounds__(256) void k4_out(const float* __restrict__ hmax, const float* __restrict__ hmin,
                                              const float* __restrict__ scale, const float* __restrict__ shift,
                                              float* __restrict__ out) {
    int e = blockIdx.x * 256 + threadIdx.x;
    int q = e >> 7, c = e & 127;
    int half = (q >= M1) ? 1 : 0;
    float a = scale[half*128 + c], b = shift[half*128 + c];
    float v = (a >= 0.0f) ? hmax[e] : hmin[e];
    float r = fmaxf(0.0f, a*v + b);
    int off = half ? (OUT_X2 + (q - M1)*128 + c) : (OUT_X1 + q*128 + c);
    out[off] = r;
}

extern "C" void kernel_launch(void* const* d_in, const int* in_sizes, int n_in,
                              void* d_out, int out_size, void* d_ws, size_t ws_size,
                              hipStream_t stream) {
    const float* p     = (const float*)d_in[0];
    const float* x     = (const float*)d_in[1];
    const float* W     = (const float*)d_in[3];
    const float* gamma = (const float*)d_in[4];
    const float* beta  = (const float*)d_in[5];
    float* out = (float*)d_out;

    float* wsf  = (float*)d_ws;
    float* sump = wsf;                 // 16384
    float* px   = wsf + 16384;
    float* py   = wsf + 32768;
    float* pz   = wsf + 49152;
    int*   fidx = (int*)(wsf + 65536); // 8192
    int*   knn  = (int*)(wsf + 73728); // 131072
    float* hmax = wsf + 204800;        // 1048576
    float* hmin = wsf + 1253376;       // 1048576
    // k1 scratch overlaid on hmax region (dead before k3 writes hmax)
    float* rxp  = hmax;                // 16384
    float* ryp  = hmax + 16384;
    float* rzp  = hmax + 32768;
    int*   ridp = (int*)(hmax + 49152);
    int*   flag = (int*)(wsf + 270336); // inside hmax region, past rid; dead before k3
    double* psum = (double*)((char*)d_ws + 9207808);
    double* psq  = psum + 65536;
    float* scale = (float*)(psq + 65536);
    float* shift = scale + 256;

    k0_init <<<64,   256, 0, stream>>>(p, sump, px, py, pz, out, flag, fidx);
    k1_fps  <<<256, 1024, 0, stream>>>(p, rxp, ryp, rzp, ridp, fidx, out, flag, px, py, pz, sump, knn);
    k3_gemm <<<512,  128, 0, stream>>>(p, x, W, fidx, knn, hmax, hmin, psum, psq);
    k35_stats<<<1,   256, 0, stream>>>(psum, psq, gamma, beta, scale, shift);
    k4_out  <<<4096, 256, 0, stream>>>(hmax, hmin, scale, shift, out);
}

// Round 10
// 5277.571 us; speedup vs baseline: 1.0930x; 1.0431x over previous
//
#include <hip/hip_runtime.h>

#define N_PTS 16384
#define M_TOTAL 8192
#define M1 4096

// output offsets (floats)
#define OUT_NP   0
#define OUT_X1   12288
#define OUT_NO   536576
#define OUT_NP2  536577
#define OUT_X2   548865
#define OUT_NO2  1073153

#define POOL_C 64

// ---------------- K0: |p|^2, SoA copy, n_o outputs, flag + fidx + BN-acc init ----------------
__global__ void k0_init(const float* __restrict__ p, float* __restrict__ sump,
                        float* __restrict__ px, float* __restrict__ py, float* __restrict__ pz,
                        float* __restrict__ out, int* __restrict__ flag, int* __restrict__ fidx,
                        double* __restrict__ bn) {
    int i = blockIdx.x * 256 + threadIdx.x;
    if (i == 0) { out[OUT_NO] = 4096.0f; out[OUT_NO2] = 4096.0f; atomicExch(flag, 0); }
    if (i < 512) bn[i] = 0.0;                       // [0..255]=sum(half,c), [256..511]=sumsq
    if (i < M_TOTAL) fidx[i] = (i == 0) ? 0 : -1;   // -1 = not yet produced (worker handshake)
    if (i < N_PTS) {
        float x = p[3*i], y = p[3*i+1], z = p[3*i+2];
        px[i] = x; py[i] = y; pz[i] = z;
        sump[i] = __fadd_rn(__fadd_rn(__fmul_rn(x,x), __fmul_rn(y,y)), __fmul_rn(z,z));
    }
}

__device__ __forceinline__ unsigned spread4(unsigned v) {
    return (v & 1u) | ((v & 2u) << 2) | ((v & 4u) << 4) | ((v & 8u) << 6);
}
// exact lower bound: rn ops, monotone rounding => d2bb <= d2(p,q) for p in bbox
__device__ __forceinline__ float bb_d2(float qx, float qy, float qz,
                                       float mnx, float mxx, float mny, float mxy,
                                       float mnz, float mxz) {
    float ax = fmaxf(fmaxf(__fsub_rn(mnx, qx), __fsub_rn(qx, mxx)), 0.0f);
    float ay = fmaxf(fmaxf(__fsub_rn(mny, qy), __fsub_rn(qy, mxy)), 0.0f);
    float az = fmaxf(fmaxf(__fsub_rn(mnz, qz), __fsub_rn(qz, mxz)), 0.0f);
    return __fadd_rn(__fadd_rn(__fmul_rn(ax,ax), __fmul_rn(ay,ay)), __fmul_rn(az,az));
}
// exact np replication: (dx*dx + dy*dy) + dz*dz, rn, no FMA
__device__ __forceinline__ float pt_d2(float ax, float ay, float az,
                                       float bx, float by, float bz) {
    float dx = __fsub_rn(ax,bx), dy = __fsub_rn(ay,by), dz = __fsub_rn(az,bz);
    return __fadd_rn(__fadd_rn(__fmul_rn(dx,dx), __fmul_rn(dy,dy)), __fmul_rn(dz,dz));
}
// wave64 max via DPP (row_shr 1,2,4,8 ; row_bcast15 ; row_bcast31), broadcast from lane63
__device__ __forceinline__ float wave_max64(float v) {
    v = fmaxf(v, __int_as_float(__builtin_amdgcn_update_dpp(0, __float_as_int(v), 0x111, 0xf, 0xf, true)));
    v = fmaxf(v, __int_as_float(__builtin_amdgcn_update_dpp(0, __float_as_int(v), 0x112, 0xf, 0xf, true)));
    v = fmaxf(v, __int_as_float(__builtin_amdgcn_update_dpp(0, __float_as_int(v), 0x114, 0xf, 0xf, true)));
    v = fmaxf(v, __int_as_float(__builtin_amdgcn_update_dpp(0, __float_as_int(v), 0x118, 0xf, 0xf, true)));
    v = fmaxf(v, __int_as_float(__builtin_amdgcn_update_dpp(0, __float_as_int(v), 0x142, 0xf, 0xf, true)));
    v = fmaxf(v, __int_as_float(__builtin_amdgcn_update_dpp(0, __float_as_int(v), 0x143, 0xf, 0xf, true)));
    return __int_as_float(__builtin_amdgcn_readlane(__float_as_int(v), 63));
}

// ---------------- K1: FPS (block 0) + KNN+GEMM workers (blocks 1..255, waves 0..3) + heaters ----------------
__global__ __launch_bounds__(1024) void k1_fps(
    const float* __restrict__ p,
    float* __restrict__ rx, float* __restrict__ ry, float* __restrict__ rz,
    int* __restrict__ rid,
    int* __restrict__ fidx, float* __restrict__ out, int* __restrict__ flag,
    const float* __restrict__ px, const float* __restrict__ py,
    const float* __restrict__ pz, const float* __restrict__ sump,
    const float* __restrict__ xin, const float* __restrict__ W,
    float* __restrict__ hmax, float* __restrict__ hmin,
    double* __restrict__ bn)
{
    int tid = threadIdx.x, lane = tid & 63, wv = tid >> 6;

    __shared__ int hist[4096];
    __shared__ float sred[16][6];
    __shared__ int wsum[16];
    __shared__ float4 pool4[POOL_C];     // x,y,z,d
    __shared__ unsigned ppk[POOL_C];     // rid
    __shared__ float4 barr4[POOL_C+1];   // batch winner coords
    __shared__ unsigned skeys[POOL_C];   // batch winner rids (batched fidx publish)
    __shared__ float fdv[16];
    __shared__ unsigned fdk[16];
    __shared__ unsigned mcell;
    __shared__ float s_invm;
    __shared__ int s_cutbin;
    __shared__ unsigned s_cutbits;
    __shared__ unsigned s_fkey;
    __shared__ int bcnt, tcell;
    __shared__ float sdk[4][16][64];     // worker KNN merge (waves 0..3)
    __shared__ int   sik[4][16][64];

    if (blockIdx.x != 0) {
        // workers + heaters: keep chip busy (clocks); workers do KNN + fused linear/max as fidx[q] arrives
        float a0 = 1.0f + tid, a1 = 2.0f, a2 = 3.0f, a3 = 4.0f;
        const float hb = 1.0000001f, hc = 1e-9f;
        if (wv < 4) {
            int g = (blockIdx.x - 1) * 4 + wv;            // 0..1019
            for (int jq = 0; jq < 9; ++jq) {
                int q = g + 1020 * jq;
                if (q >= M_TOTAL) break;
                // wait until FPS produced fidx[q] (slot self-validating: != -1)
                int qi = -1;
                for (;;) {
                    if (lane == 0)
                        qi = __hip_atomic_load(&fidx[q], __ATOMIC_RELAXED, __HIP_MEMORY_SCOPE_AGENT);
                    qi = __shfl(qi, 0);
                    if (qi >= 0) break;
#pragma unroll
                    for (int u = 0; u < 256; ++u) {
                        a0 = __fmaf_rn(a0, hb, hc); a1 = __fmaf_rn(a1, hb, hc);
                        a2 = __fmaf_rn(a2, hb, hc); a3 = __fmaf_rn(a3, hb, hc);
                    }
                }
                // ---- KNN for query q (exact old k2 scan) ----
                float qx = px[qi], qy = py[qi], qz = pz[qi], sq = sump[qi];
                float bd[16]; int bi[16];
#pragma unroll
                for (int k = 0; k < 16; ++k) { bd[k] = 3.4e38f; bi[k] = 0x7fffffff; }
                for (int j0 = 0; j0 < N_PTS; j0 += 64) {
                    int j = j0 + lane;
                    float dot = __fmaf_rn(pz[j], qz, __fmaf_rn(py[j], qy, __fmul_rn(px[j], qx)));
                    float d = __fadd_rn(__fsub_rn(sq, __fmul_rn(2.0f, dot)), sump[j]);
                    if (d < bd[15]) {
                        float cdv = d; int ci = j;
#pragma unroll
                        for (int k = 0; k < 16; ++k) {
                            if (cdv < bd[k]) { float td = bd[k]; int ti = bi[k]; bd[k] = cdv; bi[k] = ci; cdv = td; ci = ti; }
                        }
                    }
                }
#pragma unroll
                for (int k = 0; k < 16; ++k) { sdk[wv][k][lane] = bd[k]; sik[wv][k][lane] = bi[k]; }
                // merge: winner mi at each rank is wave-uniform (full shuffle reduction) -> registers
                int njr[16];
                int pos = 0;
#pragma unroll
                for (int r = 0; r < 16; ++r) {
                    float hd = (pos < 16) ? sdk[wv][pos][lane] : 3.4e38f;
                    int   hi2 = (pos < 16) ? sik[wv][pos][lane] : 0x7fffffff;
                    float md = hd; int mi = hi2;
#pragma unroll
                    for (int off = 1; off < 64; off <<= 1) {
                        float od = __shfl_xor(md, off);
                        int   oi = __shfl_xor(mi, off);
                        if (od < md || (od == md && oi < mi)) { md = od; mi = oi; }
                    }
                    if (hi2 == mi && pos < 16) pos++;
                    njr[r] = mi;
                }

                // ---- fused k3: per-(q,c) linear + max/min + BN f64 partials ----
                // lane = channel c (0..63) and c+64; feats read from global (same addr across lanes = broadcast)
                float hmx0 = -3.4e38f, hmn0 = 3.4e38f, hmx1 = -3.4e38f, hmn1 = 3.4e38f;
                double sm0 = 0.0, sq0 = 0.0, sm1 = 0.0, sq1 = 0.0;
#pragma unroll
                for (int s2 = 0; s2 < 16; ++s2) {
                    int nj = njr[s2];
                    float acc0 = 0.0f, acc1 = 0.0f;
                    // j = 0,1,2 : relative coords (identical fma order to old k3: j ascending)
                    {
                        float f0 = p[3*nj+0] - qx;
                        acc0 = __fmaf_rn(f0, W[0*128 + lane], acc0);
                        acc1 = __fmaf_rn(f0, W[0*128 + 64 + lane], acc1);
                        float f1 = p[3*nj+1] - qy;
                        acc0 = __fmaf_rn(f1, W[1*128 + lane], acc0);
                        acc1 = __fmaf_rn(f1, W[1*128 + 64 + lane], acc1);
                        float f2 = p[3*nj+2] - qz;
                        acc0 = __fmaf_rn(f2, W[2*128 + lane], acc0);
                        acc1 = __fmaf_rn(f2, W[2*128 + 64 + lane], acc1);
                    }
                    const float* xr = &xin[nj*64];
                    for (int j = 3; j < 67; ++j) {
                        float f = xr[j-3];
                        acc0 = __fmaf_rn(f, W[j*128 + lane], acc0);
                        acc1 = __fmaf_rn(f, W[j*128 + 64 + lane], acc1);
                    }
                    // (old k3's j=67 term was fma(0,0,acc): exact no-op, skipped)
                    hmx0 = fmaxf(hmx0, acc0); hmn0 = fminf(hmn0, acc0);
                    hmx1 = fmaxf(hmx1, acc1); hmn1 = fminf(hmn1, acc1);
                    sm0 += (double)acc0; sq0 += (double)acc0 * (double)acc0;
                    sm1 += (double)acc1; sq1 += (double)acc1 * (double)acc1;
                }
                hmax[q*128 + lane]      = hmx0;  hmax[q*128 + 64 + lane] = hmx1;
                hmin[q*128 + lane]      = hmn0;  hmin[q*128 + 64 + lane] = hmn1;
                int hb2 = (q >= M1) ? 128 : 0;
                atomicAdd(&bn[hb2 + lane],            sm0);
                atomicAdd(&bn[hb2 + 64 + lane],       sm1);
                atomicAdd(&bn[256 + hb2 + lane],      sq0);
                atomicAdd(&bn[256 + hb2 + 64 + lane], sq1);
            }
        }
        // heater until FPS done
        for (;;) {
#pragma unroll
            for (int u = 0; u < 512; ++u) {
                a0 = __fmaf_rn(a0, hb, hc); a1 = __fmaf_rn(a1, hb, hc);
                a2 = __fmaf_rn(a2, hb, hc); a3 = __fmaf_rn(a3, hb, hc);
            }
            int done = 0;
            if (lane == 0)
                done = __hip_atomic_load(flag, __ATOMIC_RELAXED, __HIP_MEMORY_SCOPE_AGENT);
            done = __shfl(done, 0);
            if (done) break;
        }
        __asm__ volatile("" :: "v"(a0), "v"(a1), "v"(a2), "v"(a3));
        return;
    }

    // ======== Morton sort ========
    float mnx = 3.4e38f, mny = 3.4e38f, mnz = 3.4e38f;
    float mxx = -3.4e38f, mxy = -3.4e38f, mxz = -3.4e38f;
#pragma unroll
    for (int k = 0; k < 16; ++k) {
        int i = tid + 1024*k;
        float x = p[3*i], y = p[3*i+1], z = p[3*i+2];
        mnx = fminf(mnx, x); mxx = fmaxf(mxx, x);
        mny = fminf(mny, y); mxy = fmaxf(mxy, y);
        mnz = fminf(mnz, z); mxz = fmaxf(mxz, z);
    }
#pragma unroll
    for (int off = 1; off < 64; off <<= 1) {
        mnx = fminf(mnx, __shfl_xor(mnx, off)); mxx = fmaxf(mxx, __shfl_xor(mxx, off));
        mny = fminf(mny, __shfl_xor(mny, off)); mxy = fmaxf(mxy, __shfl_xor(mxy, off));
        mnz = fminf(mnz, __shfl_xor(mnz, off)); mxz = fmaxf(mxz, __shfl_xor(mxz, off));
    }
    if (lane == 0) {
        sred[wv][0] = mnx; sred[wv][1] = mxx; sred[wv][2] = mny;
        sred[wv][3] = mxy; sred[wv][4] = mnz; sred[wv][5] = mxz;
    }
    for (int j = tid; j < 4096; j += 1024) hist[j] = 0;
    __syncthreads();
    mnx = sred[0][0]; mxx = sred[0][1]; mny = sred[0][2];
    mxy = sred[0][3]; mnz = sred[0][4]; mxz = sred[0][5];
    for (int w2 = 1; w2 < 16; ++w2) {
        mnx = fminf(mnx, sred[w2][0]); mxx = fmaxf(mxx, sred[w2][1]);
        mny = fminf(mny, sred[w2][2]); mxy = fmaxf(mxy, sred[w2][3]);
        mnz = fminf(mnz, sred[w2][4]); mxz = fmaxf(mxz, sred[w2][5]);
    }
    float sx = 16.0f / fmaxf(mxx - mnx, 1e-20f);
    float sy = 16.0f / fmaxf(mxy - mny, 1e-20f);
    float sz = 16.0f / fmaxf(mxz - mnz, 1e-20f);

    int mcode[16];
#pragma unroll
    for (int k = 0; k < 16; ++k) {
        int i = tid + 1024*k;
        float x = p[3*i], y = p[3*i+1], z = p[3*i+2];
        int cx = min(15, (int)((x - mnx) * sx));
        int cy = min(15, (int)((y - mny) * sy));
        int cz = min(15, (int)((z - mnz) * sz));
        int m = (int)(spread4((unsigned)cx) | (spread4((unsigned)cy) << 1) | (spread4((unsigned)cz) << 2));
        mcode[k] = m;
        atomicAdd(&hist[m], 1);
    }
    __syncthreads();
    {
        int c0 = hist[4*tid], c1 = hist[4*tid+1], c2 = hist[4*tid+2], c3 = hist[4*tid+3];
        int lsum = c0 + c1 + c2 + c3;
        int incl = lsum;
#pragma unroll
        for (int off = 1; off < 64; off <<= 1) {
            int n = __shfl_up(incl, off);
            if (lane >= off) incl += n;
        }
        if (lane == 63) wsum[wv] = incl;
        __syncthreads();
        int woff = 0;
        for (int j = 0; j < wv; ++j) woff += wsum[j];
        int excl = woff + incl - lsum;
        hist[4*tid]   = excl;
        hist[4*tid+1] = excl + c0;
        hist[4*tid+2] = excl + c0 + c1;
        hist[4*tid+3] = excl + c0 + c1 + c2;
    }
    __syncthreads();
#pragma unroll
    for (int k = 0; k < 16; ++k) {
        int i = tid + 1024*k;
        int pos = atomicAdd(&hist[mcode[k]], 1);
        rx[pos] = p[3*i]; ry[pos] = p[3*i+1]; rz[pos] = p[3*i+2];
        rid[pos] = i;
    }
    __syncthreads();

    // ======== per-thread group state ========
    int base = tid * 16;
    float ld[16];
    float bmnx = 3.4e38f, bmny = 3.4e38f, bmnz = 3.4e38f;
    float bmxx = -3.4e38f, bmxy = -3.4e38f, bmxz = -3.4e38f;
#pragma unroll
    for (int k = 0; k < 16; ++k) {
        float x = rx[base+k], y = ry[base+k], z = rz[base+k];
        ld[k] = 1e10f;
        bmnx = fminf(bmnx, x); bmxx = fmaxf(bmxx, x);
        bmny = fminf(bmny, y); bmxy = fmaxf(bmxy, y);
        bmnz = fminf(bmnz, z); bmxz = fmaxf(bmxz, z);
    }
    float wsmnx = bmnx, wsmxx = bmxx, wsmny = bmny, wsmxy = bmxy, wsmnz = bmnz, wsmxz = bmxz;
#pragma unroll
    for (int off = 1; off < 64; off <<= 1) {
        wsmnx = fminf(wsmnx, __shfl_xor(wsmnx, off)); wsmxx = fmaxf(wsmxx, __shfl_xor(wsmxx, off));
        wsmny = fminf(wsmny, __shfl_xor(wsmny, off)); wsmxy = fmaxf(wsmxy, __shfl_xor(wsmxy, off));
        wsmnz = fminf(wsmnz, __shfl_xor(wsmnz, off)); wsmxz = fmaxf(wsmxz, __shfl_xor(wsmxz, off));
    }
    float gmax = 1e10f, wave_gmax = 1e10f;

    if (tid == 0) {
        float x0 = p[0], y0 = p[1], z0 = p[2];
        out[OUT_NP+0] = x0; out[OUT_NP+1] = y0; out[OUT_NP+2] = z0;
        barr4[0] = make_float4(x0, y0, z0, 0.0f);
        skeys[0] = 0u;
        bcnt = 1; tcell = 1; mcell = 0u;
    }

    // ======== main refresh loop ========
    for (;;) {
        __syncthreads();                                  // B1
        int t_now = tcell;
        int s = bcnt;
        // batched fidx publish of the batch that just finished selection: [t_now - s, t_now)
        if (tid < s)
            __hip_atomic_store(&fidx[t_now - s + tid], (int)skeys[tid], __ATOMIC_RELAXED, __HIP_MEMORY_SCOPE_AGENT);
        if (t_now >= M_TOTAL) break;

        // ---- apply batch (s <= 64: single ballot chunk); lazy coord load for dirty waves ----
        {
            bool dirtyw = false;
            if (lane < s) {
                float4 cc = barr4[lane];
                dirtyw = bb_d2(cc.x, cc.y, cc.z, wsmnx, wsmxx, wsmny, wsmxy, wsmnz, wsmxz) < wave_gmax;
            }
            unsigned long long mm = __ballot(dirtyw);
            if (mm) {
                float gx[16], gy[16], gz[16];
#pragma unroll
                for (int k = 0; k < 16; ++k) { gx[k] = rx[base+k]; gy[k] = ry[base+k]; gz[k] = rz[base+k]; }
                while (mm) {
                    int b = __builtin_ctzll(mm); mm &= mm - 1;
                    float4 cc = barr4[b];
                    if (bb_d2(cc.x, cc.y, cc.z, bmnx, bmxx, bmny, bmxy, bmnz, bmxz) < gmax) {
#pragma unroll
                        for (int k = 0; k < 16; ++k)
                            ld[k] = fminf(ld[k], pt_d2(gx[k], gy[k], gz[k], cc.x, cc.y, cc.z));
                    }
                }
            }
        }
        gmax = ld[0];
#pragma unroll
        for (int k = 1; k < 16; ++k) gmax = fmaxf(gmax, ld[k]);
        wave_gmax = wave_max64(gmax);
        if (lane == 0) atomicMax(&mcell, __float_as_uint(wave_gmax));
        if (tid < 130) hist[tid] = 0;
        __syncthreads();                                  // B2
        if (tid == 0) { s_invm = 1.0f / __uint_as_float(mcell); mcell = 0u; }
        __syncthreads();                                  // B3
        float invm = s_invm;
        // filtered histogram: only r >= 0.5 (129 fine bins over [0.5, 1])
#pragma unroll
        for (int k = 0; k < 16; ++k) {
            unsigned u = __float_as_uint(__fmul_rn(ld[k], invm));
            if (u >= 0x3F000000u) {
                int bin = 16256 - (int)(u >> 16);
                bin = bin < 0 ? 0 : (bin > 128 ? 128 : bin);
                atomicAdd(&hist[bin], 1);
            }
        }
        __syncthreads();                                  // B4
        if (wv == 0) {
            int b0 = hist[2*lane], b1 = hist[2*lane+1];   // bins 0..127
            int pair = b0 + b1;
            int incl = pair;
#pragma unroll
            for (int off = 1; off < 64; off <<= 1) { int n = __shfl_up(incl, off); if (lane >= off) incl += n; }
            int before = incl - pair;
            int cb = 0;
            if (before + b0 <= POOL_C) cb = 2*lane + 1;
            if (before + pair <= POOL_C) cb = 2*lane + 2;
            if (lane == 63) { if (incl + hist[128] <= POOL_C) cb = 129; }
#pragma unroll
            for (int off = 1; off < 64; off <<= 1) cb = max(cb, __shfl_xor(cb, off));
            if (lane == 0) { s_cutbin = cb; s_cutbits = (unsigned)(16257 - cb) << 16; }
        }
        __syncthreads();                                  // B5

        // ---- compact-count (runs in degenerate case too; cheap) ----
        unsigned cutbits = s_cutbits;
        int cl = 0;
#pragma unroll
        for (int k = 0; k < 16; ++k)
            cl += (__float_as_uint(__fmul_rn(ld[k], invm)) >= cutbits) ? 1 : 0;
        int inc3 = cl;
#pragma unroll
        for (int off = 1; off < 64; off <<= 1) { int n = __shfl_up(inc3, off); if (lane >= off) inc3 += n; }
        if (lane == 63) wsum[wv] = inc3;
        __syncthreads();                                  // B6
        int woff2 = 0, ptot = 0;
        for (int j = 0; j < 16; ++j) { int wsj = wsum[j]; if (j < wv) woff2 += wsj; ptot += wsj; }

        if (s_cutbin == 0 || ptot == 0) {
            // degenerate / empty-pool guard: one exact full argmax step (guaranteed progress)
            float bv = -1.0f; unsigned bk = 0xffffffffu;
#pragma unroll
            for (int k = 0; k < 16; ++k) {
                unsigned kk = ((unsigned)rid[base+k] << 14) | (unsigned)(base + k);
                bool better = (ld[k] > bv) || (ld[k] == bv && kk < bk);
                bv = better ? ld[k] : bv; bk = better ? kk : bk;
            }
#pragma unroll
            for (int off = 1; off < 64; off <<= 1) {
                float ov = __shfl_xor(bv, off); unsigned ok = __shfl_xor(bk, off);
                bool better = (ov > bv) || (ov == bv && ok < bk);
                bv = better ? ov : bv; bk = better ? ok : bk;
            }
            if (lane == 0) { fdv[wv] = bv; fdk[wv] = bk; }
            __syncthreads();
            if (tid < 64) {
                float v2 = (tid < 16) ? fdv[tid] : -1.0f;
                unsigned k2v = (tid < 16) ? fdk[tid] : 0xffffffffu;
#pragma unroll
                for (int off = 1; off < 16; off <<= 1) {
                    float ov = __shfl_xor(v2, off); unsigned ok = __shfl_xor(k2v, off);
                    bool better = (ov > v2) || (ov == v2 && ok < k2v);
                    v2 = better ? ov : v2; k2v = better ? ok : k2v;
                }
                if (tid == 0) {
                    s_fkey = k2v;
                    int pos = (int)(k2v & 16383u);
                    __hip_atomic_store(&fidx[t_now], (int)(k2v >> 14), __ATOMIC_RELAXED, __HIP_MEMORY_SCOPE_AGENT);
                    float wx = rx[pos], wy = ry[pos], wz = rz[pos];
                    int o = (t_now < M1) ? (OUT_NP + 3*t_now) : (OUT_NP2 + 3*(t_now - M1));
                    out[o] = wx; out[o+1] = wy; out[o+2] = wz;
                    tcell = t_now + 1; bcnt = 0;
                }
            }
            __syncthreads();
            {
                int pos = (int)(s_fkey & 16383u);
                float wx = rx[pos], wy = ry[pos], wz = rz[pos];
                if (bb_d2(wx, wy, wz, bmnx, bmxx, bmny, bmxy, bmnz, bmxz) < gmax) {
#pragma unroll
                    for (int k = 0; k < 16; ++k)
                        ld[k] = fminf(ld[k], pt_d2(rx[base+k], ry[base+k], rz[base+k], wx, wy, wz));
                }
            }
            continue;
        }

        // ---- compact pool (<= 64 entries; same bit predicate as histogram) ----
        int nb = woff2 + inc3 - cl;
#pragma unroll
        for (int k = 0; k < 16; ++k) {
            if (__float_as_uint(__fmul_rn(ld[k], invm)) >= cutbits) {
                pool4[nb] = make_float4(rx[base+k], ry[base+k], rz[base+k], ld[k]);
                ppk[nb] = (unsigned)rid[base+k];
                nb++;
            }
        }
        if (tid >= ptot && tid < POOL_C) {
            pool4[tid] = make_float4(0.0f, 0.0f, 0.0f, 0.0f);   // dv=0: never selected (cut > 0)
            ppk[tid] = 0x7fffffffu;
        }
        __syncthreads();                                  // B7

        // ---- serial selection in wave 0: ONE pool entry per lane ----
        if (wv == 0) {
            __builtin_amdgcn_s_setprio(3);
            float4 e = pool4[lane];
            float ex = e.x, ey = e.y, ez = e.z, dv = e.w;
            unsigned key = ppk[lane];
            int tl = t_now, bc = 0;
            float mw = wave_max64(dv);
            while (__float_as_uint(__fmul_rn(mw, invm)) >= cutbits) {
                unsigned long long tie = __ballot(dv == mw);
                int wl;
                if (__popcll(tie) == 1) {
                    wl = (int)__builtin_ctzll(tie);
                } else {
                    unsigned kk = (dv == mw) ? key : 0xffffffffu;
#pragma unroll
                    for (int off = 1; off < 64; off <<= 1) kk = min(kk, (unsigned)__shfl_xor((int)kk, off));
                    tie = __ballot(dv == mw && key == kk);
                    wl = (int)__builtin_ctzll(tie);
                }
                float wx = __int_as_float(__builtin_amdgcn_readlane(__float_as_int(ex), wl));
                float wy = __int_as_float(__builtin_amdgcn_readlane(__float_as_int(ey), wl));
                float wz = __int_as_float(__builtin_amdgcn_readlane(__float_as_int(ez), wl));
                unsigned wk = (unsigned)__builtin_amdgcn_readlane((int)key, wl);
                if (lane == 0) {
                    skeys[bc] = wk;                      // staged; published at next refresh (off serial chain)
                    int o = (tl < M1) ? (OUT_NP + 3*tl) : (OUT_NP2 + 3*(tl - M1));
                    out[o] = wx; out[o+1] = wy; out[o+2] = wz;
                    barr4[bc] = make_float4(wx, wy, wz, 0.0f);
                }
                ++bc; ++tl;
                if (tl >= M_TOTAL) break;
                dv = fminf(dv, pt_d2(ex, ey, ez, wx, wy, wz));   // winner lane -> 0 (self)
                mw = wave_max64(dv);
            }
            __builtin_amdgcn_s_setprio(0);
            if (lane == 0) { bcnt = bc; tcell = tl; }
        }
    }

    if (tid == 0) atomicExch(flag, 1);   // release workers/heaters
}

// ---------------- K3.5: BN stats finalize -> per-channel scale/shift ----------------
__global__ void k35_stats(const double* __restrict__ bn,
                          const float* __restrict__ gamma, const float* __restrict__ beta,
                          float* __restrict__ scale, float* __restrict__ shift) {
    int t = threadIdx.x;               // 0..255 ; t = half*128 + c
    int c = t & 127;
    double mean = bn[t] / 65536.0;
    double var  = bn[256 + t] / 65536.0 - mean*mean;
    double sc   = (double)gamma[c] / sqrt(var + 1e-5);
    scale[t] = (float)sc;
    shift[t] = (float)((double)beta[c] - mean*sc);
}

// ---------------- K4: affine + relu on max/min -> x1/x2 ----------------
__global__ __launch_bounds__(256) void k4_out(const float* __restrict__ hmax, const float* __restrict__ hmin,
                                              const float* __restrict__ scale, const float* __restrict__ shift,
                                              float* __restrict__ out) {
    int e = blockIdx.x * 256 + threadIdx.x;
    int q = e >> 7, c = e & 127;
    int half = (q >= M1) ? 1 : 0;
    float a = scale[half*128 + c], b = shift[half*128 + c];
    float v = (a >= 0.0f) ? hmax[e] : hmin[e];
    float r = fmaxf(0.0f, a*v + b);
    int off = half ? (OUT_X2 + (q - M1)*128 + c) : (OUT_X1 + q*128 + c);
    out[off] = r;
}

extern "C" void kernel_launch(void* const* d_in, const int* in_sizes, int n_in,
                              void* d_out, int out_size, void* d_ws, size_t ws_size,
                              hipStream_t stream) {
    const float* p     = (const float*)d_in[0];
    const float* x     = (const float*)d_in[1];
    const float* W     = (const float*)d_in[3];
    const float* gamma = (const float*)d_in[4];
    const float* beta  = (const float*)d_in[5];
    float* out = (float*)d_out;

    float* wsf  = (float*)d_ws;
    float* sump = wsf;                 // 16384
    float* px   = wsf + 16384;
    float* py   = wsf + 32768;
    float* pz   = wsf + 49152;
    int*   fidx = (int*)(wsf + 65536); // 8192
    float* hmax = wsf + 204800;        // 1048576 (worker-written during k1; no scratch overlay)
    float* hmin = wsf + 1253376;       // 1048576 (ends at byte 9207808)
    // k1 FPS scratch in the region freed by deleting psum/psq (byte 9207808+)
    float* rxp  = (float*)((char*)d_ws + 9207808);   // 16384 f
    float* ryp  = rxp + 16384;
    float* rzp  = ryp + 16384;
    int*   ridp = (int*)(rzp + 16384);               // 16384 i
    int*   flag = (int*)(ridp + 16384);              // 1 i
    double* bn  = (double*)((char*)d_ws + 9207808 + 4*65536 + 256); // 512 f64 (8B-aligned)
    float* scale = (float*)(bn + 512);               // 256
    float* shift = scale + 256;                      // 256

    k0_init <<<64,   256, 0, stream>>>(p, sump, px, py, pz, out, flag, fidx, bn);
    k1_fps  <<<256, 1024, 0, stream>>>(p, rxp, ryp, rzp, ridp, fidx, out, flag,
                                       px, py, pz, sump, x, W, hmax, hmin, bn);
    k35_stats<<<1,   256, 0, stream>>>(bn, gamma, beta, scale, shift);
    k4_out  <<<4096, 256, 0, stream>>>(hmax, hmin, scale, shift, out);
}